// Round 9
// baseline (52.729 us; speedup 1.0000x reference)
//
#include <hip/hip_runtime.h>
#include <math.h>

#define BB 4
#define CC 256
#define HW (128*128)
#define NC 19
#define NV 50
#define PP 950
#define INV_T (1.0f/0.07f)
#define PLANE ((size_t)BB * PP * CC)
#define NCG 8                // col groups of 128 (nce)
#define LDSP 40              // padded halves per col (32 k + 8 pad)
#define NSC 16               // 1024-px superchunks per image
#define MAXE 128             // max entries per superchunk (lambda=59.4)

typedef short bf16x8 __attribute__((ext_vector_type(8)));
typedef float f32x4  __attribute__((ext_vector_type(4)));
typedef short short4v __attribute__((ext_vector_type(4)));

static __device__ __forceinline__ unsigned short f2bf(float f) {
    unsigned int u = __float_as_uint(f);
    unsigned int r = (u + 0x7fffu + ((u >> 16) & 1u)) >> 16;   // RNE
    return (unsigned short)r;
}
static __device__ __forceinline__ float bf2f(unsigned short h) {
    return __uint_as_float(((unsigned int)h) << 16);
}
__device__ __forceinline__ void lse_merge(float& m, float& s, float m2, float s2) {
    float nm = fmaxf(m, m2);
    float e1 = __expf(m - nm);          // finite sentinels (-1e30), no NaN
    float e2 = __expf(m2 - nm);
    s = s * e1 + s2 * e2;
    m = nm;
}

// ---------------- mapbuild: per-(b,superchunk) compacted (slot,px_local) lists ----------------
__global__ __launch_bounds__(1024)
void mapbuild_kernel(const int* __restrict__ sidx,
                     int* __restrict__ clist, int* __restrict__ ccnt) {
    __shared__ int lcnt[NSC];
    __shared__ int lent[NSC * MAXE];
    int b = blockIdx.x;
    int tid = threadIdx.x;
    if (tid < NSC) lcnt[tid] = 0;
    __syncthreads();
    if (tid < PP) {
        int pix = sidx[b * PP + tid];
        int sc = pix >> 10, pl = pix & 1023;
        int pos = atomicAdd(&lcnt[sc], 1);
        if (pos < MAXE) lent[sc * MAXE + pos] = (tid << 10) | pl;
    }
    __syncthreads();
    if (tid < NSC) {
        int c = lcnt[tid];
        ccnt[b * NSC + tid] = c < MAXE ? c : MAXE;
    }
    for (int i = tid; i < NSC * MAXE; i += 1024)
        clist[b * NSC * MAXE + i] = lent[i];
}

// ---------------- gather: deep-MLP sequential stream, XCD-pinned channel bands ----------------
#define GLOAD(BUF, C) do {                                                      \
    _Pragma("unroll")                                                           \
    for (int i = 0; i < 4; ++i) {                                               \
        BUF[i]     = *(const float4*)(s0 + (C) * 256 + i * 64);                 \
        BUF[4 + i] = *(const float4*)(s1 + (C) * 256 + i * 64);                 \
    }                                                                           \
} while (0)

#define GPROC(BUF, C) do {                                                      \
    _Pragma("unroll")                                                           \
    for (int half = 0; half < 2; ++half) {                                      \
        int lch = chl + half * 16;                                              \
        _Pragma("unroll")                                                       \
        for (int i = 0; i < 4; ++i) {                                           \
            int pxl = (C) * 256 + i * 64 + lp * 4;                              \
            short4v mp = *(const short4v*)&pxmap[pxl];                          \
            float4 v = BUF[half * 4 + i];                                       \
            _Pragma("unroll")                                                   \
            for (int e = 0; e < 4; ++e) {                                       \
                int le = mp[e];                                                 \
                if (le >= 0) {                                                  \
                    float val = ((const float*)&v)[e];                          \
                    unsigned short h = f2bf(val);                               \
                    bufh[le][lch] = (short)h;                                   \
                    bufl[le][lch] = (short)f2bf(val - bf2f(h));                 \
                }                                                               \
            }                                                                   \
        }                                                                       \
    }                                                                           \
} while (0)

__global__ __launch_bounds__(256)
void gather_kernel(const float* __restrict__ fq, const float* __restrict__ fk,
                   const int* __restrict__ clist, const int* __restrict__ ccnt,
                   unsigned short* __restrict__ xqh, unsigned short* __restrict__ xql,
                   unsigned short* __restrict__ xkh, unsigned short* __restrict__ xkl) {
    __shared__ short pxmap[1024];
    __shared__ short slotarr[MAXE];
    __shared__ short bufh[MAXE][32];
    __shared__ short bufl[MAXE][32];

    int x = blockIdx.x;                 // cg(3 lo: XCD pin) | sc(4) | t(1) | b(2 hi)
    int cg     = x & 7;
    int sc     = (x >> 3) & 15;
    int tensor = (x >> 7) & 1;
    int b      = x >> 8;

    int tid = threadIdx.x;
    int cnt = ccnt[b * NSC + sc];

    if (tid < 128) ((int4*)pxmap)[tid] = make_int4(-1, -1, -1, -1);
    __syncthreads();
    if (tid < cnt) {
        int e = clist[(b * NSC + sc) * MAXE + tid];
        slotarr[tid] = (short)(e >> 10);
        pxmap[e & 1023] = (short)tid;
    }
    __syncthreads();

    const float* f = tensor ? fk : fq;
    unsigned short* oh = tensor ? xkh : xqh;
    unsigned short* ol = tensor ? xkl : xql;

    int lp = tid & 15, chl = tid >> 4;
    int ch0 = cg * 32 + chl, ch1 = ch0 + 16;
    const float* s0 = f + ((size_t)b * CC + ch0) * HW + sc * 1024 + lp * 4;
    const float* s1 = f + ((size_t)b * CC + ch1) * HW + sc * 1024 + lp * 4;

    float4 va[8], vb[8];
    GLOAD(va, 0); GLOAD(vb, 1);
    GPROC(va, 0); GLOAD(va, 2);
    GPROC(vb, 1); GLOAD(vb, 3);
    GPROC(va, 2); GPROC(vb, 3);
    __syncthreads();

    // flush: (entry, plane, 16B quarter) -> coalesced 64B-per-entry stores
#pragma unroll
    for (int r = 0; r < 4; ++r) {
        int entry = r * 32 + (tid >> 3);
        int plane = (tid >> 2) & 1, q = tid & 3;
        if (entry < cnt) {
            int slot = slotarr[entry];
            size_t dst = ((size_t)b * PP + slot) * CC + cg * 32 + q * 8;
            const short* sp = (plane ? &bufl[entry][0] : &bufh[entry][0]) + q * 8;
            *(int4*)((plane ? ol : oh) + dst) = *(const int4*)sp;
        }
    }
}

// ---------------- nce: LDS-staged block GEMM 128x128, 8 waves, dbuf k-steps ----------------
#define MF(ACC, AF, BF) ACC = __builtin_amdgcn_mfma_f32_16x16x32_bf16(AF, BF, ACC, 0, 0, 0)

#define STEP(KT) do {                                                           \
    int4 rh_, rl_;                                                              \
    if ((KT) < 7) {                                                             \
        rh_ = *(const int4*)(xkh + stage_src + ((KT) + 1) * 32);                \
        rl_ = *(const int4*)(xkl + stage_src + ((KT) + 1) * 32);                \
    }                                                                           \
    const short* bbase_ = &bl[(KT) & 1][0][0] + lr * LDSP + lg * 8;             \
    _Pragma("unroll")                                                           \
    for (int ct = 0; ct < 8; ++ct) {                                            \
        const short* bp_ = bbase_ + ct * (16 * LDSP);                           \
        bf16x8 Bh_ = *(const bf16x8*)bp_;                                       \
        bf16x8 Bl_ = *(const bf16x8*)(bp_ + 128 * LDSP);                        \
        MF(acc[ct], Ah[KT], Bh_);                                               \
        MF(acc[ct], Al[KT], Bh_);                                               \
        MF(acc[ct], Ah[KT], Bl_);                                               \
    }                                                                           \
    if ((KT) < 7) {                                                             \
        *(int4*)&bl[((KT) + 1) & 1][0][stage_dst] = rh_;                        \
        *(int4*)&bl[((KT) + 1) & 1][1][stage_dst] = rl_;                        \
        __syncthreads();                                                        \
    }                                                                           \
} while (0)

__global__ __launch_bounds__(512)
void nce_mfma(const unsigned short* __restrict__ xqh, const unsigned short* __restrict__ xql,
              const unsigned short* __restrict__ xkh, const unsigned short* __restrict__ xkl,
              float* __restrict__ pos, float* __restrict__ pm, float* __restrict__ ps) {
    __shared__ short bl[2][2][128 * LDSP];      // 40 KB: [dbuf][plane][col*LDSP+k]

    int cg = blockIdx.x;
    int rb = blockIdx.y;
    int b  = blockIdx.z;
    int tid = threadIdx.x;
    int w = tid >> 6, l = tid & 63;
    int lr = l & 15, lg = l >> 4;

    int uc = tid >> 2, uq = tid & 3;
    int gcol = cg * 128 + uc; if (gcol > PP - 1) gcol = PP - 1;
    size_t stage_src = ((size_t)b * PP + gcol) * CC + uq * 8;
    int stage_dst = uc * LDSP + uq * 8;

    int arow = rb * 128 + w * 16 + lr; if (arow > PP - 1) arow = PP - 1;
    size_t abase = ((size_t)b * PP + arow) * CC + lg * 8;
    bf16x8 Ah[8], Al[8];
#pragma unroll
    for (int kt = 0; kt < 8; ++kt) {
        Ah[kt] = *(const bf16x8*)(xqh + abase + kt * 32);
        Al[kt] = *(const bf16x8*)(xql + abase + kt * 32);
    }

    {
        int4 rh = *(const int4*)(xkh + stage_src);
        int4 rl = *(const int4*)(xkl + stage_src);
        *(int4*)&bl[0][0][stage_dst] = rh;
        *(int4*)&bl[0][1][stage_dst] = rl;
    }
    __syncthreads();

    f32x4 acc[8];
#pragma unroll
    for (int ct = 0; ct < 8; ++ct) acc[ct] = (f32x4){0.f, 0.f, 0.f, 0.f};

    STEP(0); STEP(1); STEP(2); STEP(3);
    STEP(4); STEP(5); STEP(6); STEP(7);

#pragma unroll
    for (int j = 0; j < 4; ++j) {
        int row = rb * 128 + w * 16 + lg * 4 + j;
        bool rowok = row < PP;
        int rcls = row / NV;
        float m = -1e30f, s = 0.f;
#pragma unroll
        for (int ct = 0; ct < 8; ++ct) {
            int col = cg * 128 + ct * 16 + lr;
            bool colok = col < PP;
            int ccls = col / NV;
            float x = acc[ct][j] * INV_T;
            bool ok = rowok && colok && ((ccls != rcls) || (col == row));
            if (rowok && col == row) pos[(size_t)b * 960 + row] = x;
            float xm = ok ? x : -1e30f;
            float nm = fmaxf(m, xm);
            float e1 = __expf(m - nm);
            float e2 = ok ? __expf(x - nm) : 0.f;
            s = s * e1 + e2; m = nm;
        }
#pragma unroll
        for (int off = 1; off <= 8; off <<= 1) {
            float m2 = __shfl_xor(m, off, 64);
            float s2 = __shfl_xor(s, off, 64);
            lse_merge(m, s, m2, s2);
        }
        if (lr == 0 && rowok) {
            pm[((size_t)b * NCG + cg) * 960 + row] = m;
            ps[((size_t)b * NCG + cg) * 960 + row] = s;
        }
    }
}

__global__ __launch_bounds__(256)
void finalize_kernel(const float* __restrict__ pm, const float* __restrict__ ps,
                     const float* __restrict__ pos, float* __restrict__ out) {
    int i = blockIdx.x * 256 + threadIdx.x;
    if (i >= BB * PP) return;
    int b = i / PP, row = i - b * PP;
    float m = -1e30f, s = 0.f;
#pragma unroll
    for (int g = 0; g < NCG; ++g) {
        size_t o = ((size_t)b * NCG + g) * 960 + row;
        lse_merge(m, s, pm[o], ps[o]);
    }
    out[i] = m + logf(s) - pos[(size_t)b * 960 + row];
}

extern "C" void kernel_launch(void* const* d_in, const int* in_sizes, int n_in,
                              void* d_out, int out_size, void* d_ws, size_t ws_size,
                              hipStream_t stream) {
    const float* fq   = (const float*)d_in[0];
    const float* fk   = (const float*)d_in[1];
    const int*   sidx = (const int*)d_in[2];
    float* outp = (float*)d_out;

    char* p = (char*)d_ws;
    unsigned short* xqh = (unsigned short*)p; p += PLANE * 2;
    unsigned short* xql = (unsigned short*)p; p += PLANE * 2;
    unsigned short* xkh = (unsigned short*)p; p += PLANE * 2;
    unsigned short* xkl = (unsigned short*)p; p += PLANE * 2;
    int*          clist = (int*)p;            p += (size_t)BB * NSC * MAXE * 4;
    int*           ccnt = (int*)p;            p += (size_t)BB * NSC * 4;
    float*          pos = (float*)p;          p += (size_t)BB * 960 * 4;
    float*           pm = (float*)p;          p += (size_t)BB * NCG * 960 * 4;
    float*           ps = (float*)p;

    mapbuild_kernel<<<dim3(BB), 1024, 0, stream>>>(sidx, clist, ccnt);
    gather_kernel<<<dim3(1024), 256, 0, stream>>>(fq, fk, clist, ccnt, xqh, xql, xkh, xkl);
    nce_mfma<<<dim3(NCG, 8, BB), 512, 0, stream>>>(xqh, xql, xkh, xkl, pos, pm, ps);
    finalize_kernel<<<dim3((BB * PP + 255) / 256), 256, 0, stream>>>(pm, ps, pos, outp);
}